// Round 16
// baseline (148.614 us; speedup 1.0000x reference)
//
#include <hip/hip_runtime.h>

// SGC: out = A_norm^2 (x W) + bias   (linearity: A^2 x W = A^2 (xW)).
// N=100000 nodes, E=1000000 edges, D=64 features, fp32 in/out.
// CSR build = two-level LDS-binned counting sort, ZERO per-edge global
// atomics. Round-16: hops back to QUAD-node (r14 sweet spot: octo's
// max-degree padding tax beat its instruction savings) + DEGREE-GROUPED
// scheduling: kB_sort emits perm[] (nodes sorted by degree within each
// bucket) so the 4 nodes sharing a wave have near-equal degrees and
// padding collapses.

constexpr int kN = 100000;
constexpr int kD = 64;
constexpr int BSHIFT = 9;                    // 512 nodes per coarse bucket
constexpr int NBUCK = (kN + 511) >> BSHIFT;  // 196
constexpr int CHUNK = 4096;                  // pass-A edges per block
constexpr int XW_ROWS = 128;                 // k_xw rows per block
constexpr int ECW_PAD = 256;                 // zeroed tail pad (ecw overrun)

__device__ __forceinline__ unsigned short f2bf(float f) {  // RNE
    unsigned b = __float_as_uint(f);
    b += 0x7FFF + ((b >> 16) & 1);
    return (unsigned short)(b >> 16);
}
__device__ __forceinline__ float lo16(unsigned u) {
    return __uint_as_float(u << 16);
}
__device__ __forceinline__ float hi16(unsigned u) {
    return __uint_as_float(u & 0xffff0000u);
}

// ---- fused: y = x@W (blocks [0,nxw)) + per-chunk bucket histogram ----
__global__ __launch_bounds__(256) void k_xw_count(const float* __restrict__ x,
                                                  const float* __restrict__ W,
                                                  unsigned short* __restrict__ y,
                                                  const int* __restrict__ row,
                                                  int* __restrict__ bc,
                                                  int* __restrict__ done,
                                                  int nxw, int nblk, int n, int E) {
    __shared__ float Xs[XW_ROWS][kD];  // count role reuses first 1KB as hist
    int bid = blockIdx.x;
    int t = threadIdx.x;
    if (bid == 0 && t == 0) *done = 0;  // for kA_scan's last-block detect
    if (bid >= nxw) {
        // ---- histogram role (1 chunk of 4096 edges) ----
        int cb = bid - nxw;
        int* hist = (int*)&Xs[0][0];
        hist[t] = 0;
        __syncthreads();
        int g0 = cb * CHUNK;
        int nn = min(CHUNK, E - g0);
        for (int i = t; i < nn; i += 256) {
            atomicAdd(&hist[row[g0 + i] >> BSHIFT], 1);
        }
        __syncthreads();
        if (t < NBUCK) bc[t * nblk + cb] = hist[t];
        return;
    }
    // ---- GEMM role: lane = out column (W col in VGPRs), rows in LDS ----
    int lane = t & 63;
    int wv = t >> 6;
    int row0 = bid * XW_ROWS;
    float Wc[kD];
#pragma unroll
    for (int k = 0; k < kD; ++k) Wc[k] = W[k * kD + lane];
    for (int i = t; i < XW_ROWS * (kD / 4); i += 256) {
        int r = i >> 4;
        int q = i & 15;
        float4 v = make_float4(0.0f, 0.0f, 0.0f, 0.0f);
        if (row0 + r < n)
            v = *reinterpret_cast<const float4*>(x + (size_t)(row0 + r) * kD + q * 4);
        *reinterpret_cast<float4*>(&Xs[r][q * 4]) = v;
    }
    __syncthreads();
    int rbase = wv * 32;
#pragma unroll
    for (int rr = 0; rr < 32; rr += 2) {
        int r0 = rbase + rr;
        float acc0 = 0.0f, acc1 = 0.0f;
#pragma unroll
        for (int q = 0; q < 16; ++q) {  // broadcast reads
            float4 a = *reinterpret_cast<const float4*>(&Xs[r0][q * 4]);
            float4 b = *reinterpret_cast<const float4*>(&Xs[r0 + 1][q * 4]);
            acc0 = fmaf(a.x, Wc[q * 4 + 0], acc0);
            acc1 = fmaf(b.x, Wc[q * 4 + 0], acc1);
            acc0 = fmaf(a.y, Wc[q * 4 + 1], acc0);
            acc1 = fmaf(b.y, Wc[q * 4 + 1], acc1);
            acc0 = fmaf(a.z, Wc[q * 4 + 2], acc0);
            acc1 = fmaf(b.z, Wc[q * 4 + 2], acc1);
            acc0 = fmaf(a.w, Wc[q * 4 + 3], acc0);
            acc1 = fmaf(b.w, Wc[q * 4 + 3], acc1);
        }
        int gr = row0 + r0;
        if (gr < n) y[(size_t)gr * kD + lane] = f2bf(acc0);
        if (gr + 1 < n) y[(size_t)(gr + 1) * kD + lane] = f2bf(acc1);
    }
}

// ---- pass A2: per-bucket scan over blocks + (last block) bucket-base scan
__global__ __launch_bounds__(256) void kA_scan(int* __restrict__ bc,
                                               int* __restrict__ tot,
                                               int* __restrict__ base,
                                               int2* __restrict__ ecw_pad,
                                               int* __restrict__ done, int nblk) {
    __shared__ int sh[256];
    __shared__ int lastflag;
    int b = blockIdx.x;
    int t = threadIdx.x;
    int* p = bc + (size_t)b * nblk;
    int ipt = (nblk + 255) >> 8;
    int s0 = t * ipt;
    int s1 = min(s0 + ipt, nblk);
    int lsum = 0;
    for (int k = s0; k < s1; ++k) lsum += p[k];
    sh[t] = lsum;
    __syncthreads();
    for (int off = 1; off < 256; off <<= 1) {
        int add = (t >= off) ? sh[t - off] : 0;
        __syncthreads();
        sh[t] += add;
        __syncthreads();
    }
    int run = sh[t] - lsum;
    for (int k = s0; k < s1; ++k) {
        int v = p[k];
        p[k] = run;
        run += v;
    }
    if (t == 255) tot[b] = sh[255];
    __threadfence();  // make tot[b] (and bc) visible device-wide
    __syncthreads();
    if (t == 0) lastflag = (atomicAdd(done, 1) == NBUCK - 1);
    __syncthreads();
    if (lastflag) {
        int v = (t < NBUCK) ? atomicAdd(&tot[t], 0) : 0;
        sh[t] = v;
        __syncthreads();
        for (int off = 1; off < 256; off <<= 1) {
            int add = (t >= off) ? sh[t - off] : 0;
            __syncthreads();
            sh[t] += add;
            __syncthreads();
        }
        if (t < NBUCK) base[t] = sh[t] - v;
        ecw_pad[t] = make_int2(0, 0);  // ecw-overrun region, weight 0
    }
}

// ---- pass A3: bucket-major placement via LDS staging, coalesced run flush
// tmp[pos] = { col | (row&511)<<17 , w_bits }
__global__ __launch_bounds__(256) void kA_place(const int* __restrict__ row,
                                                const int* __restrict__ col,
                                                const float* __restrict__ w,
                                                const int* __restrict__ bc,
                                                const int* __restrict__ base, int nblk,
                                                int2* __restrict__ tmp, int E) {
    __shared__ int hist[256];
    __shared__ int lbase[256];
    __shared__ int gb[256];
    __shared__ int cur[256];
    __shared__ int2 stage[CHUNK];
    __shared__ unsigned char bkt[CHUNK];
    int t = threadIdx.x;
    hist[t] = 0;
    __syncthreads();
    int g0 = blockIdx.x * CHUNK;
    int n = min(CHUNK, E - g0);
    for (int i = t; i < n; i += 256) {
        atomicAdd(&hist[row[g0 + i] >> BSHIFT], 1);
    }
    __syncthreads();
    int v = hist[t];
    lbase[t] = v;
    __syncthreads();
    for (int off = 1; off < 256; off <<= 1) {
        int add = (t >= off) ? lbase[t - off] : 0;
        __syncthreads();
        lbase[t] += add;
        __syncthreads();
    }
    int excl = lbase[t] - v;
    __syncthreads();
    lbase[t] = excl;
    cur[t] = excl;
    if (t < NBUCK) gb[t] = base[t] + bc[t * nblk + blockIdx.x];
    __syncthreads();
    for (int i = t; i < n; i += 256) {
        int r = row[g0 + i];
        int c = col[g0 + i];
        float wv = w[g0 + i];
        int b = r >> BSHIFT;
        int lp = atomicAdd(&cur[b], 1);
        stage[lp] = make_int2(c | ((r & 511) << 17), __float_as_int(wv));
        bkt[lp] = (unsigned char)b;
    }
    __syncthreads();
    for (int i = t; i < n; i += 256) {
        int b = bkt[i];
        tmp[gb[b] + (i - lbase[b])] = stage[i];
    }
}

// ---- pass A4: per-bucket deg/dinv from tmp (LDS float atomics) ----
__global__ __launch_bounds__(512) void kD_deg(const int2* __restrict__ tmp,
                                              const int* __restrict__ base,
                                              float* __restrict__ dinv, int E) {
    __shared__ float degs[512];
    int b = blockIdx.x;
    int t = threadIdx.x;
    degs[t] = 0.0f;
    __syncthreads();
    int gbase = base[b];
    int gend = (b == NBUCK - 1) ? E : base[b + 1];
    int node0 = b << BSHIFT;
    int nloc = min(512, kN - node0);
    for (int i = gbase + t; i < gend; i += 512) {
        int2 e = tmp[i];
        atomicAdd(&degs[(e.x >> 17) & 511], __int_as_float(e.y));
    }
    __syncthreads();
    if (t < nloc) {
        float d = 1.0f + degs[t];
        dinv[node0 + t] = (d > 0.0f) ? rsqrtf(d) : 0.0f;
    }
}

// ---- pass B: per-bucket fine counting sort + start[] + degree-perm ----
// writes FINAL ecw = {byte offset col<<7, dinv[row]*w*dinv[col]} and
// perm[] = node ids sorted by ascending degree within each bucket.
__global__ __launch_bounds__(512) void kB_sort(const int2* __restrict__ tmp,
                                               const int* __restrict__ base,
                                               const float* __restrict__ dinv,
                                               int2* __restrict__ ecw,
                                               int* __restrict__ start,
                                               int* __restrict__ perm, int E) {
    __shared__ int hist[512];
    __shared__ int cur[512];
    __shared__ int deg[512];
    int b = blockIdx.x;
    int t = threadIdx.x;
    int gbase = base[b];
    int gend = (b == NBUCK - 1) ? E : base[b + 1];
    int size = gend - gbase;
    int node0 = b << BSHIFT;
    int nloc = min(512, kN - node0);
    hist[t] = 0;
    __syncthreads();
    for (int i = t; i < size; i += 512) {
        atomicAdd(&hist[(tmp[gbase + i].x >> 17) & 511], 1);
    }
    __syncthreads();
    int v = hist[t];
    deg[t] = v;  // save node degree for the perm sort
    hist[t] = v;
    __syncthreads();
    for (int off = 1; off < 512; off <<= 1) {
        int add = (t >= off) ? hist[t - off] : 0;
        __syncthreads();
        hist[t] += add;
        __syncthreads();
    }
    int excl = hist[t] - v;
    __syncthreads();
    cur[t] = excl;
    __syncthreads();
    if (t < nloc) start[node0 + t] = gbase + excl;
    if (b == 0 && t == 0) start[kN] = E;
    // scatter within bucket, applying full normalization
    for (int i = t; i < size; i += 512) {
        int2 e = tmp[gbase + i];
        int c = e.x & 0x1FFFF;
        int rl = (e.x >> 17) & 511;
        float wn = dinv[node0 + rl] * __int_as_float(e.y) * dinv[c];
        int lp = atomicAdd(&cur[rl], 1);
        ecw[gbase + lp] = make_int2(c << 7, __float_as_int(wn));
    }
    __syncthreads();
    // ---- degree-grouping perm: counting sort of local nodes by degree ----
    hist[t] = 0;
    __syncthreads();
    int db = min(deg[t], 511);
    if (t < nloc) atomicAdd(&hist[db], 1);
    __syncthreads();
    int v2 = hist[t];
    __syncthreads();
    for (int off = 1; off < 512; off <<= 1) {
        int add = (t >= off) ? hist[t - off] : 0;
        __syncthreads();
        hist[t] += add;
        __syncthreads();
    }
    int dexcl = hist[t] - v2;
    __syncthreads();
    cur[t] = dexcl;
    __syncthreads();
    if (t < nloc) {
        int pos = atomicAdd(&cur[db], 1);
        perm[node0 + pos] = node0 + t;
    }
}

// ---- quad-node gather hop over degree-sorted perm ----
// 4 nodes/wave, 16 lanes each, lane=feature quad (bf16x4 8B gathers).
// node = perm[slot]: wave-mates have near-equal degree -> minimal padding.
// Padded slots gather addr 0 (hot line) with weight 0 (exact).
template <typename OutWriter>
__device__ __forceinline__ void hop_body(const int* __restrict__ start,
                                         const int2* __restrict__ ecw,
                                         const float* __restrict__ dinv,
                                         const unsigned short* __restrict__ h_in,
                                         const int* __restrict__ perm,
                                         int n, OutWriter writeout) {
    int wv = threadIdx.x >> 6;
    int lane = threadIdx.x & 63;
    int q = lane >> 4;   // node-in-wave 0..3
    int f = lane & 15;   // feature quad (features 4f..4f+3)
    int slot = blockIdx.x * 16 + wv * 4 + q;
    bool valid = slot < n;
    int nd = perm[min(slot, n - 1)];
    const char* hb = (const char*)h_in;
    int lo = f << 3;  // byte offset of the feature quad in a 128B row
    float di = dinv[nd];
    float d2 = di * di;
    uint2 su = *(const uint2*)(hb + ((size_t)nd << 7) + lo);
    float acc0 = d2 * lo16(su.x);
    float acc1 = d2 * hi16(su.x);
    float acc2 = d2 * lo16(su.y);
    float acc3 = d2 * hi16(su.y);
    int s = start[nd], e = start[nd + 1];
    int d = e - s;
    int m1 = max(d, __shfl_xor(d, 16));
    int dmax = max(m1, __shfl_xor(m1, 32));  // uniform loop bound
    for (int it = 0; it < dmax; it += 4) {
        int j = s + it;
        int2 v0 = ecw[j + 0];  // unconditional: tail pad makes overrun safe
        int2 v1 = ecw[j + 1];
        int2 v2 = ecw[j + 2];
        int2 v3 = ecw[j + 3];
        bool p0 = (it + 0 < d), p1 = (it + 1 < d);
        bool p2 = (it + 2 < d), p3 = (it + 3 < d);
        unsigned o0 = p0 ? (unsigned)v0.x : 0u;  // pad -> hot line 0
        unsigned o1 = p1 ? (unsigned)v1.x : 0u;
        unsigned o2 = p2 ? (unsigned)v2.x : 0u;
        unsigned o3 = p3 ? (unsigned)v3.x : 0u;
        uint2 g0 = *(const uint2*)(hb + (o0 + lo));
        uint2 g1 = *(const uint2*)(hb + (o1 + lo));
        uint2 g2 = *(const uint2*)(hb + (o2 + lo));
        uint2 g3 = *(const uint2*)(hb + (o3 + lo));
        float w0 = p0 ? __int_as_float(v0.y) : 0.0f;
        float w1 = p1 ? __int_as_float(v1.y) : 0.0f;
        float w2 = p2 ? __int_as_float(v2.y) : 0.0f;
        float w3 = p3 ? __int_as_float(v3.y) : 0.0f;
        acc0 = fmaf(w0, lo16(g0.x), acc0);
        acc1 = fmaf(w0, hi16(g0.x), acc1);
        acc2 = fmaf(w0, lo16(g0.y), acc2);
        acc3 = fmaf(w0, hi16(g0.y), acc3);
        acc0 = fmaf(w1, lo16(g1.x), acc0);
        acc1 = fmaf(w1, hi16(g1.x), acc1);
        acc2 = fmaf(w1, lo16(g1.y), acc2);
        acc3 = fmaf(w1, hi16(g1.y), acc3);
        acc0 = fmaf(w2, lo16(g2.x), acc0);
        acc1 = fmaf(w2, hi16(g2.x), acc1);
        acc2 = fmaf(w2, lo16(g2.y), acc2);
        acc3 = fmaf(w2, hi16(g2.y), acc3);
        acc0 = fmaf(w3, lo16(g3.x), acc0);
        acc1 = fmaf(w3, hi16(g3.x), acc1);
        acc2 = fmaf(w3, lo16(g3.y), acc2);
        acc3 = fmaf(w3, hi16(g3.y), acc3);
    }
    if (valid) writeout(nd, f, acc0, acc1, acc2, acc3);
}

__global__ __launch_bounds__(256) void k_hop1(const int* __restrict__ start,
                                              const int2* __restrict__ ecw,
                                              const float* __restrict__ dinv,
                                              const unsigned short* __restrict__ h_in,
                                              const int* __restrict__ perm,
                                              uint2* __restrict__ h_out64, int n) {
    hop_body(start, ecw, dinv, h_in, perm, n,
             [=](int node, int f, float a0, float a1, float a2, float a3) {
                 uint2 p;
                 p.x = (unsigned)f2bf(a0) | ((unsigned)f2bf(a1) << 16);
                 p.y = (unsigned)f2bf(a2) | ((unsigned)f2bf(a3) << 16);
                 h_out64[((size_t)node << 4) + f] = p;  // 16 uint2 per row
             });
}

__global__ __launch_bounds__(256) void k_hop2(const int* __restrict__ start,
                                              const int2* __restrict__ ecw,
                                              const float* __restrict__ dinv,
                                              const unsigned short* __restrict__ h_in,
                                              const int* __restrict__ perm,
                                              const float* __restrict__ bias,
                                              float* __restrict__ out, int n) {
    hop_body(start, ecw, dinv, h_in, perm, n,
             [=](int node, int f, float a0, float a1, float a2, float a3) {
                 float4 b = *reinterpret_cast<const float4*>(bias + (f << 2));
                 float4 o = make_float4(a0 + b.x, a1 + b.y, a2 + b.z, a3 + b.w);
                 *reinterpret_cast<float4*>(out + ((size_t)node << 6) + (f << 2)) = o;
             });
}

extern "C" void kernel_launch(void* const* d_in, const int* in_sizes, int n_in,
                              void* d_out, int out_size, void* d_ws, size_t ws_size,
                              hipStream_t stream) {
    const float* x    = (const float*)d_in[0];   // (N, 64)
    const int*   ei   = (const int*)d_in[1];     // (2, E)
    const float* ew   = (const float*)d_in[2];   // (E,)
    const float* W    = (const float*)d_in[3];   // (64, 64)
    const float* bias = (const float*)d_in[4];   // (64,)
    const int E = in_sizes[1] / 2;
    const int* row = ei;       // destination
    const int* col = ei + E;   // source

    const int nblk = (E + CHUNK - 1) / CHUNK;        // 245 @ E=1M
    const int nxw  = (kN + XW_ROWS - 1) / XW_ROWS;   // 782

    // ws layout (1KB-aligned): base[256] | tot[256] | done | bc[NBUCK*nblk]
    // | start[kN+1] | perm[kN] | dinv[kN] | ecw[E+pad] int2 | y bf16 |
    // h1 bf16 (tmp aliases h1)
    char* ws = (char*)d_ws;
    auto alloc = [&](size_t bytes) {
        char* p = ws;
        ws += ((bytes + 1023) & ~(size_t)1023);
        return p;
    };
    int*            base  = (int*)alloc(sizeof(int) * 256);
    int*            tot   = (int*)alloc(sizeof(int) * 256);
    int*            done  = (int*)alloc(sizeof(int) * 64);
    int*            bc    = (int*)alloc(sizeof(int) * (size_t)NBUCK * nblk);
    int*            start = (int*)alloc(sizeof(int) * (kN + 1));
    int*            perm  = (int*)alloc(sizeof(int) * kN);
    float*          dinv  = (float*)alloc(sizeof(float) * kN);
    int2*           ecw   = (int2*)alloc(sizeof(int2) * (size_t)(E + ECW_PAD));
    unsigned short* y     = (unsigned short*)alloc(sizeof(short) * (size_t)kN * kD);
    unsigned short* h1    = (unsigned short*)alloc(sizeof(short) * (size_t)kN * kD);
    int2*           tmp   = (int2*)h1;  // bucket-major staging, dead before hop1

    // fused: y = x@W  ||  per-chunk bucket histogram (+ done=0)
    k_xw_count<<<nxw + nblk, 256, 0, stream>>>(x, W, y, row, bc, done,
                                               nxw, nblk, kN, E);

    // CSR build (no per-edge global atomics)
    kA_scan<<<NBUCK, 256, 0, stream>>>(bc, tot, base, ecw + E, done, nblk);
    kA_place<<<nblk, 256, 0, stream>>>(row, col, ew, bc, base, nblk, tmp, E);
    kD_deg<<<NBUCK, 512, 0, stream>>>(tmp, base, dinv, E);
    kB_sort<<<NBUCK, 512, 0, stream>>>(tmp, base, dinv, ecw, start, perm, E);

    // 2 gather hops (quad-node waves over degree-sorted perm)
    k_hop1<<<(kN + 15) / 16, 256, 0, stream>>>(start, ecw, dinv, y, perm,
                                               (uint2*)h1, kN);
    k_hop2<<<(kN + 15) / 16, 256, 0, stream>>>(start, ecw, dinv, h1, perm,
                                               bias, (float*)d_out, kN);
}

// Round 17
// 134.935 us; speedup vs baseline: 1.1014x; 1.1014x over previous
//
#include <hip/hip_runtime.h>

// SGC: out = A_norm^2 (x W) + bias   (linearity: A^2 x W = A^2 (xW)).
// N=100000 nodes, E=1000000 edges, D=64 features, fp32 in/out.
// CSR build = two-level LDS-binned counting sort, ZERO per-edge global
// atomics. Round-17: revert to r14's proven optimum (quad-node hops in
// NATURAL node order -- r16's degree-perm destroyed ecw/store locality,
// r15's octo-node paid a max-degree padding tax). Kept from r15/r16:
// merged single-launch kA_scan + hot-line-0 padding in the hop.

constexpr int kN = 100000;
constexpr int kD = 64;
constexpr int BSHIFT = 9;                    // 512 nodes per coarse bucket
constexpr int NBUCK = (kN + 511) >> BSHIFT;  // 196
constexpr int CHUNK = 4096;                  // pass-A edges per block
constexpr int XW_ROWS = 128;                 // k_xw rows per block
constexpr int ECW_PAD = 256;                 // zeroed tail pad (ecw overrun)

__device__ __forceinline__ unsigned short f2bf(float f) {  // RNE
    unsigned b = __float_as_uint(f);
    b += 0x7FFF + ((b >> 16) & 1);
    return (unsigned short)(b >> 16);
}
__device__ __forceinline__ float lo16(unsigned u) {
    return __uint_as_float(u << 16);
}
__device__ __forceinline__ float hi16(unsigned u) {
    return __uint_as_float(u & 0xffff0000u);
}

// ---- fused: y = x@W (blocks [0,nxw)) + per-chunk bucket histogram ----
__global__ __launch_bounds__(256) void k_xw_count(const float* __restrict__ x,
                                                  const float* __restrict__ W,
                                                  unsigned short* __restrict__ y,
                                                  const int* __restrict__ row,
                                                  int* __restrict__ bc,
                                                  int* __restrict__ done,
                                                  int nxw, int nblk, int n, int E) {
    __shared__ float Xs[XW_ROWS][kD];  // count role reuses first 1KB as hist
    int bid = blockIdx.x;
    int t = threadIdx.x;
    if (bid == 0 && t == 0) *done = 0;  // for kA_scan's last-block detect
    if (bid >= nxw) {
        // ---- histogram role (1 chunk of 4096 edges) ----
        int cb = bid - nxw;
        int* hist = (int*)&Xs[0][0];
        hist[t] = 0;
        __syncthreads();
        int g0 = cb * CHUNK;
        int nn = min(CHUNK, E - g0);
        for (int i = t; i < nn; i += 256) {
            atomicAdd(&hist[row[g0 + i] >> BSHIFT], 1);
        }
        __syncthreads();
        if (t < NBUCK) bc[t * nblk + cb] = hist[t];
        return;
    }
    // ---- GEMM role: lane = out column (W col in VGPRs), rows in LDS ----
    int lane = t & 63;
    int wv = t >> 6;
    int row0 = bid * XW_ROWS;
    float Wc[kD];
#pragma unroll
    for (int k = 0; k < kD; ++k) Wc[k] = W[k * kD + lane];
    for (int i = t; i < XW_ROWS * (kD / 4); i += 256) {
        int r = i >> 4;
        int q = i & 15;
        float4 v = make_float4(0.0f, 0.0f, 0.0f, 0.0f);
        if (row0 + r < n)
            v = *reinterpret_cast<const float4*>(x + (size_t)(row0 + r) * kD + q * 4);
        *reinterpret_cast<float4*>(&Xs[r][q * 4]) = v;
    }
    __syncthreads();
    int rbase = wv * 32;
#pragma unroll
    for (int rr = 0; rr < 32; rr += 2) {
        int r0 = rbase + rr;
        float acc0 = 0.0f, acc1 = 0.0f;
#pragma unroll
        for (int q = 0; q < 16; ++q) {  // broadcast reads
            float4 a = *reinterpret_cast<const float4*>(&Xs[r0][q * 4]);
            float4 b = *reinterpret_cast<const float4*>(&Xs[r0 + 1][q * 4]);
            acc0 = fmaf(a.x, Wc[q * 4 + 0], acc0);
            acc1 = fmaf(b.x, Wc[q * 4 + 0], acc1);
            acc0 = fmaf(a.y, Wc[q * 4 + 1], acc0);
            acc1 = fmaf(b.y, Wc[q * 4 + 1], acc1);
            acc0 = fmaf(a.z, Wc[q * 4 + 2], acc0);
            acc1 = fmaf(b.z, Wc[q * 4 + 2], acc1);
            acc0 = fmaf(a.w, Wc[q * 4 + 3], acc0);
            acc1 = fmaf(b.w, Wc[q * 4 + 3], acc1);
        }
        int gr = row0 + r0;
        if (gr < n) y[(size_t)gr * kD + lane] = f2bf(acc0);
        if (gr + 1 < n) y[(size_t)(gr + 1) * kD + lane] = f2bf(acc1);
    }
}

// ---- pass A2: per-bucket scan over blocks + (last block) bucket-base scan
__global__ __launch_bounds__(256) void kA_scan(int* __restrict__ bc,
                                               int* __restrict__ tot,
                                               int* __restrict__ base,
                                               int2* __restrict__ ecw_pad,
                                               int* __restrict__ done, int nblk) {
    __shared__ int sh[256];
    __shared__ int lastflag;
    int b = blockIdx.x;
    int t = threadIdx.x;
    int* p = bc + (size_t)b * nblk;
    int ipt = (nblk + 255) >> 8;
    int s0 = t * ipt;
    int s1 = min(s0 + ipt, nblk);
    int lsum = 0;
    for (int k = s0; k < s1; ++k) lsum += p[k];
    sh[t] = lsum;
    __syncthreads();
    for (int off = 1; off < 256; off <<= 1) {
        int add = (t >= off) ? sh[t - off] : 0;
        __syncthreads();
        sh[t] += add;
        __syncthreads();
    }
    int run = sh[t] - lsum;
    for (int k = s0; k < s1; ++k) {
        int v = p[k];
        p[k] = run;
        run += v;
    }
    if (t == 255) tot[b] = sh[255];
    __threadfence();  // make tot[b] (and bc) visible device-wide
    __syncthreads();
    if (t == 0) lastflag = (atomicAdd(done, 1) == NBUCK - 1);
    __syncthreads();
    if (lastflag) {
        int v = (t < NBUCK) ? atomicAdd(&tot[t], 0) : 0;
        sh[t] = v;
        __syncthreads();
        for (int off = 1; off < 256; off <<= 1) {
            int add = (t >= off) ? sh[t - off] : 0;
            __syncthreads();
            sh[t] += add;
            __syncthreads();
        }
        if (t < NBUCK) base[t] = sh[t] - v;
        ecw_pad[t] = make_int2(0, 0);  // ecw-overrun region, weight 0
    }
}

// ---- pass A3: bucket-major placement via LDS staging, coalesced run flush
// tmp[pos] = { col | (row&511)<<17 , w_bits }
__global__ __launch_bounds__(256) void kA_place(const int* __restrict__ row,
                                                const int* __restrict__ col,
                                                const float* __restrict__ w,
                                                const int* __restrict__ bc,
                                                const int* __restrict__ base, int nblk,
                                                int2* __restrict__ tmp, int E) {
    __shared__ int hist[256];
    __shared__ int lbase[256];
    __shared__ int gb[256];
    __shared__ int cur[256];
    __shared__ int2 stage[CHUNK];
    __shared__ unsigned char bkt[CHUNK];
    int t = threadIdx.x;
    hist[t] = 0;
    __syncthreads();
    int g0 = blockIdx.x * CHUNK;
    int n = min(CHUNK, E - g0);
    for (int i = t; i < n; i += 256) {
        atomicAdd(&hist[row[g0 + i] >> BSHIFT], 1);
    }
    __syncthreads();
    int v = hist[t];
    lbase[t] = v;
    __syncthreads();
    for (int off = 1; off < 256; off <<= 1) {
        int add = (t >= off) ? lbase[t - off] : 0;
        __syncthreads();
        lbase[t] += add;
        __syncthreads();
    }
    int excl = lbase[t] - v;
    __syncthreads();
    lbase[t] = excl;
    cur[t] = excl;
    if (t < NBUCK) gb[t] = base[t] + bc[t * nblk + blockIdx.x];
    __syncthreads();
    for (int i = t; i < n; i += 256) {
        int r = row[g0 + i];
        int c = col[g0 + i];
        float wv = w[g0 + i];
        int b = r >> BSHIFT;
        int lp = atomicAdd(&cur[b], 1);
        stage[lp] = make_int2(c | ((r & 511) << 17), __float_as_int(wv));
        bkt[lp] = (unsigned char)b;
    }
    __syncthreads();
    for (int i = t; i < n; i += 256) {
        int b = bkt[i];
        tmp[gb[b] + (i - lbase[b])] = stage[i];
    }
}

// ---- pass A4: per-bucket deg/dinv from tmp (LDS float atomics) ----
__global__ __launch_bounds__(512) void kD_deg(const int2* __restrict__ tmp,
                                              const int* __restrict__ base,
                                              float* __restrict__ dinv, int E) {
    __shared__ float degs[512];
    int b = blockIdx.x;
    int t = threadIdx.x;
    degs[t] = 0.0f;
    __syncthreads();
    int gbase = base[b];
    int gend = (b == NBUCK - 1) ? E : base[b + 1];
    int node0 = b << BSHIFT;
    int nloc = min(512, kN - node0);
    for (int i = gbase + t; i < gend; i += 512) {
        int2 e = tmp[i];
        atomicAdd(&degs[(e.x >> 17) & 511], __int_as_float(e.y));
    }
    __syncthreads();
    if (t < nloc) {
        float d = 1.0f + degs[t];
        dinv[node0 + t] = (d > 0.0f) ? rsqrtf(d) : 0.0f;
    }
}

// ---- pass B: per-bucket fine counting sort + start[] ----
// writes FINAL ecw = {byte offset col<<7, dinv[row]*w*dinv[col]}.
__global__ __launch_bounds__(512) void kB_sort(const int2* __restrict__ tmp,
                                               const int* __restrict__ base,
                                               const float* __restrict__ dinv,
                                               int2* __restrict__ ecw,
                                               int* __restrict__ start, int E) {
    __shared__ int hist[512];
    __shared__ int cur[512];
    int b = blockIdx.x;
    int t = threadIdx.x;
    int gbase = base[b];
    int gend = (b == NBUCK - 1) ? E : base[b + 1];
    int size = gend - gbase;
    int node0 = b << BSHIFT;
    int nloc = min(512, kN - node0);
    hist[t] = 0;
    __syncthreads();
    for (int i = t; i < size; i += 512) {
        atomicAdd(&hist[(tmp[gbase + i].x >> 17) & 511], 1);
    }
    __syncthreads();
    int v = hist[t];
    hist[t] = v;
    __syncthreads();
    for (int off = 1; off < 512; off <<= 1) {
        int add = (t >= off) ? hist[t - off] : 0;
        __syncthreads();
        hist[t] += add;
        __syncthreads();
    }
    int excl = hist[t] - v;
    __syncthreads();
    cur[t] = excl;
    __syncthreads();
    if (t < nloc) start[node0 + t] = gbase + excl;
    if (b == 0 && t == 0) start[kN] = E;
    for (int i = t; i < size; i += 512) {
        int2 e = tmp[gbase + i];
        int c = e.x & 0x1FFFF;
        int rl = (e.x >> 17) & 511;
        float wn = dinv[node0 + rl] * __int_as_float(e.y) * dinv[c];
        int lp = atomicAdd(&cur[rl], 1);
        ecw[gbase + lp] = make_int2(c << 7, __float_as_int(wn));
    }
}

// ---- quad-node gather hop: 4 nodes/wave, 16 lanes each, lane=feature quad
// Each lane loads a packed bf16x4 (8B). One gather + one ecw broadcast
// retire an edge-slot for all 4 nodes. Natural node order (consecutive
// nodes per wave -> contiguous ecw segments, coalesced self-reads/stores).
// Padded slots gather addr 0 (hot line) with weight 0 (exact).
template <typename OutWriter>
__device__ __forceinline__ void hop_body(const int* __restrict__ start,
                                         const int2* __restrict__ ecw,
                                         const float* __restrict__ dinv,
                                         const unsigned short* __restrict__ h_in,
                                         int n, OutWriter writeout) {
    int wv = threadIdx.x >> 6;
    int lane = threadIdx.x & 63;
    int q = lane >> 4;   // node-in-wave 0..3
    int f = lane & 15;   // feature quad (features 4f..4f+3)
    int node = blockIdx.x * 16 + wv * 4 + q;
    bool valid = node < n;
    int nd = valid ? node : (n - 1);
    const char* hb = (const char*)h_in;
    int lo = f << 3;  // byte offset of the feature quad in a 128B row
    float di = dinv[nd];
    float d2 = di * di;
    uint2 su = *(const uint2*)(hb + ((size_t)nd << 7) + lo);
    float acc0 = d2 * lo16(su.x);
    float acc1 = d2 * hi16(su.x);
    float acc2 = d2 * lo16(su.y);
    float acc3 = d2 * hi16(su.y);
    int s = start[nd], e = start[nd + 1];
    int d = e - s;
    int m1 = max(d, __shfl_xor(d, 16));
    int dmax = max(m1, __shfl_xor(m1, 32));  // uniform loop bound
    for (int it = 0; it < dmax; it += 4) {
        int j = s + it;
        int2 v0 = ecw[j + 0];  // unconditional: tail pad makes overrun safe
        int2 v1 = ecw[j + 1];
        int2 v2 = ecw[j + 2];
        int2 v3 = ecw[j + 3];
        bool p0 = (it + 0 < d), p1 = (it + 1 < d);
        bool p2 = (it + 2 < d), p3 = (it + 3 < d);
        unsigned o0 = p0 ? (unsigned)v0.x : 0u;  // pad -> hot line 0
        unsigned o1 = p1 ? (unsigned)v1.x : 0u;
        unsigned o2 = p2 ? (unsigned)v2.x : 0u;
        unsigned o3 = p3 ? (unsigned)v3.x : 0u;
        uint2 g0 = *(const uint2*)(hb + (o0 + lo));
        uint2 g1 = *(const uint2*)(hb + (o1 + lo));
        uint2 g2 = *(const uint2*)(hb + (o2 + lo));
        uint2 g3 = *(const uint2*)(hb + (o3 + lo));
        float w0 = p0 ? __int_as_float(v0.y) : 0.0f;
        float w1 = p1 ? __int_as_float(v1.y) : 0.0f;
        float w2 = p2 ? __int_as_float(v2.y) : 0.0f;
        float w3 = p3 ? __int_as_float(v3.y) : 0.0f;
        acc0 = fmaf(w0, lo16(g0.x), acc0);
        acc1 = fmaf(w0, hi16(g0.x), acc1);
        acc2 = fmaf(w0, lo16(g0.y), acc2);
        acc3 = fmaf(w0, hi16(g0.y), acc3);
        acc0 = fmaf(w1, lo16(g1.x), acc0);
        acc1 = fmaf(w1, hi16(g1.x), acc1);
        acc2 = fmaf(w1, lo16(g1.y), acc2);
        acc3 = fmaf(w1, hi16(g1.y), acc3);
        acc0 = fmaf(w2, lo16(g2.x), acc0);
        acc1 = fmaf(w2, hi16(g2.x), acc1);
        acc2 = fmaf(w2, lo16(g2.y), acc2);
        acc3 = fmaf(w2, hi16(g2.y), acc3);
        acc0 = fmaf(w3, lo16(g3.x), acc0);
        acc1 = fmaf(w3, hi16(g3.x), acc1);
        acc2 = fmaf(w3, lo16(g3.y), acc2);
        acc3 = fmaf(w3, hi16(g3.y), acc3);
    }
    if (valid) writeout(node, f, acc0, acc1, acc2, acc3);
}

__global__ __launch_bounds__(256) void k_hop1(const int* __restrict__ start,
                                              const int2* __restrict__ ecw,
                                              const float* __restrict__ dinv,
                                              const unsigned short* __restrict__ h_in,
                                              uint2* __restrict__ h_out64, int n) {
    hop_body(start, ecw, dinv, h_in, n,
             [=](int node, int f, float a0, float a1, float a2, float a3) {
                 uint2 p;
                 p.x = (unsigned)f2bf(a0) | ((unsigned)f2bf(a1) << 16);
                 p.y = (unsigned)f2bf(a2) | ((unsigned)f2bf(a3) << 16);
                 h_out64[((size_t)node << 4) + f] = p;  // 16 uint2 per row
             });
}

__global__ __launch_bounds__(256) void k_hop2(const int* __restrict__ start,
                                              const int2* __restrict__ ecw,
                                              const float* __restrict__ dinv,
                                              const unsigned short* __restrict__ h_in,
                                              const float* __restrict__ bias,
                                              float* __restrict__ out, int n) {
    hop_body(start, ecw, dinv, h_in, n,
             [=](int node, int f, float a0, float a1, float a2, float a3) {
                 float4 b = *reinterpret_cast<const float4*>(bias + (f << 2));
                 float4 o = make_float4(a0 + b.x, a1 + b.y, a2 + b.z, a3 + b.w);
                 *reinterpret_cast<float4*>(out + ((size_t)node << 6) + (f << 2)) = o;
             });
}

extern "C" void kernel_launch(void* const* d_in, const int* in_sizes, int n_in,
                              void* d_out, int out_size, void* d_ws, size_t ws_size,
                              hipStream_t stream) {
    const float* x    = (const float*)d_in[0];   // (N, 64)
    const int*   ei   = (const int*)d_in[1];     // (2, E)
    const float* ew   = (const float*)d_in[2];   // (E,)
    const float* W    = (const float*)d_in[3];   // (64, 64)
    const float* bias = (const float*)d_in[4];   // (64,)
    const int E = in_sizes[1] / 2;
    const int* row = ei;       // destination
    const int* col = ei + E;   // source

    const int nblk = (E + CHUNK - 1) / CHUNK;        // 245 @ E=1M
    const int nxw  = (kN + XW_ROWS - 1) / XW_ROWS;   // 782

    // ws layout (1KB-aligned): base[256] | tot[256] | done | bc[NBUCK*nblk]
    // | start[kN+1] | dinv[kN] | ecw[E+pad] int2 | y bf16 | h1 bf16 (tmp=h1)
    char* ws = (char*)d_ws;
    auto alloc = [&](size_t bytes) {
        char* p = ws;
        ws += ((bytes + 1023) & ~(size_t)1023);
        return p;
    };
    int*            base  = (int*)alloc(sizeof(int) * 256);
    int*            tot   = (int*)alloc(sizeof(int) * 256);
    int*            done  = (int*)alloc(sizeof(int) * 64);
    int*            bc    = (int*)alloc(sizeof(int) * (size_t)NBUCK * nblk);
    int*            start = (int*)alloc(sizeof(int) * (kN + 1));
    float*          dinv  = (float*)alloc(sizeof(float) * kN);
    int2*           ecw   = (int2*)alloc(sizeof(int2) * (size_t)(E + ECW_PAD));
    unsigned short* y     = (unsigned short*)alloc(sizeof(short) * (size_t)kN * kD);
    unsigned short* h1    = (unsigned short*)alloc(sizeof(short) * (size_t)kN * kD);
    int2*           tmp   = (int2*)h1;  // bucket-major staging, dead before hop1

    // fused: y = x@W  ||  per-chunk bucket histogram (+ done=0)
    k_xw_count<<<nxw + nblk, 256, 0, stream>>>(x, W, y, row, bc, done,
                                               nxw, nblk, kN, E);

    // CSR build (no per-edge global atomics)
    kA_scan<<<NBUCK, 256, 0, stream>>>(bc, tot, base, ecw + E, done, nblk);
    kA_place<<<nblk, 256, 0, stream>>>(row, col, ew, bc, base, nblk, tmp, E);
    kD_deg<<<NBUCK, 512, 0, stream>>>(tmp, base, dinv, E);
    kB_sort<<<NBUCK, 512, 0, stream>>>(tmp, base, dinv, ecw, start, E);

    // 2 gather hops (quad-node waves, packed bf16x4 gathers, natural order)
    k_hop1<<<(kN + 15) / 16, 256, 0, stream>>>(start, ecw, dinv, y,
                                               (uint2*)h1, kN);
    k_hop2<<<(kN + 15) / 16, 256, 0, stream>>>(start, ecw, dinv, h1, bias,
                                               (float*)d_out, kN);
}

// Round 18
// 122.509 us; speedup vs baseline: 1.2131x; 1.1014x over previous
//
#include <hip/hip_runtime.h>

// SGC: out = A_norm^2 (x W) + bias   (linearity: A^2 x W = A^2 (xW)).
// N=100000 nodes, E=1000000 edges, D=64 features, fp32 in/out.
// CSR build = two-level LDS-binned counting sort, ZERO per-edge global
// atomics. Round-18: byte-exact revert to the round-14 measured optimum
// (123.8us). r15 octo (-6.5), r16 degree-perm (-25), r17 "micro-wins"
// (-11: hot-line-0 killed the accidental next-segment prefetch; merged
// scan added a fence barrier) all measured worse. Quad-node hops,
// natural order, unconditional tail-padded ecw reads, weight-only
// predication.

constexpr int kN = 100000;
constexpr int kD = 64;
constexpr int BSHIFT = 9;                    // 512 nodes per coarse bucket
constexpr int NBUCK = (kN + 511) >> BSHIFT;  // 196
constexpr int CHUNK = 4096;                  // pass-A edges per block
constexpr int XW_ROWS = 128;                 // k_xw rows per block
constexpr int ECW_PAD = 256;                 // zeroed tail pad (overrun-safe)

__device__ __forceinline__ float bf2f(unsigned short u) {
    return __uint_as_float(((unsigned)u) << 16);
}
__device__ __forceinline__ unsigned short f2bf(float f) {  // RNE
    unsigned b = __float_as_uint(f);
    b += 0x7FFF + ((b >> 16) & 1);
    return (unsigned short)(b >> 16);
}

// ---- fused: y = x@W (blocks [0,nxw)) + per-chunk bucket histogram ----
__global__ __launch_bounds__(256) void k_xw_count(const float* __restrict__ x,
                                                  const float* __restrict__ W,
                                                  unsigned short* __restrict__ y,
                                                  const int* __restrict__ row,
                                                  int* __restrict__ bc,
                                                  int nxw, int nblk, int n, int E) {
    __shared__ float Xs[XW_ROWS][kD];  // count role reuses first 1KB as hist
    int bid = blockIdx.x;
    int t = threadIdx.x;
    if (bid >= nxw) {
        // ---- histogram role (1 chunk of 4096 edges) ----
        int cb = bid - nxw;
        int* hist = (int*)&Xs[0][0];
        hist[t] = 0;
        __syncthreads();
        int g0 = cb * CHUNK;
        int nn = min(CHUNK, E - g0);
        for (int i = t; i < nn; i += 256) {
            atomicAdd(&hist[row[g0 + i] >> BSHIFT], 1);
        }
        __syncthreads();
        if (t < NBUCK) bc[t * nblk + cb] = hist[t];
        return;
    }
    // ---- GEMM role: lane = out column (W col in VGPRs), rows in LDS ----
    int lane = t & 63;
    int wv = t >> 6;
    int row0 = bid * XW_ROWS;
    float Wc[kD];
#pragma unroll
    for (int k = 0; k < kD; ++k) Wc[k] = W[k * kD + lane];
    for (int i = t; i < XW_ROWS * (kD / 4); i += 256) {
        int r = i >> 4;
        int q = i & 15;
        float4 v = make_float4(0.0f, 0.0f, 0.0f, 0.0f);
        if (row0 + r < n)
            v = *reinterpret_cast<const float4*>(x + (size_t)(row0 + r) * kD + q * 4);
        *reinterpret_cast<float4*>(&Xs[r][q * 4]) = v;
    }
    __syncthreads();
    int rbase = wv * 32;
#pragma unroll
    for (int rr = 0; rr < 32; rr += 2) {
        int r0 = rbase + rr;
        float acc0 = 0.0f, acc1 = 0.0f;
#pragma unroll
        for (int q = 0; q < 16; ++q) {  // broadcast reads
            float4 a = *reinterpret_cast<const float4*>(&Xs[r0][q * 4]);
            float4 b = *reinterpret_cast<const float4*>(&Xs[r0 + 1][q * 4]);
            acc0 = fmaf(a.x, Wc[q * 4 + 0], acc0);
            acc1 = fmaf(b.x, Wc[q * 4 + 0], acc1);
            acc0 = fmaf(a.y, Wc[q * 4 + 1], acc0);
            acc1 = fmaf(b.y, Wc[q * 4 + 1], acc1);
            acc0 = fmaf(a.z, Wc[q * 4 + 2], acc0);
            acc1 = fmaf(b.z, Wc[q * 4 + 2], acc1);
            acc0 = fmaf(a.w, Wc[q * 4 + 3], acc0);
            acc1 = fmaf(b.w, Wc[q * 4 + 3], acc1);
        }
        int gr = row0 + r0;
        if (gr < n) y[(size_t)gr * kD + lane] = f2bf(acc0);
        if (gr + 1 < n) y[(size_t)(gr + 1) * kD + lane] = f2bf(acc1);
    }
}

// ---- pass A2a: per-bucket parallel exclusive scan over blocks ----
__global__ __launch_bounds__(256) void kA_scanB(int* __restrict__ bc,
                                                int* __restrict__ tot, int nblk) {
    __shared__ int sh[256];
    int b = blockIdx.x;
    int t = threadIdx.x;
    int* p = bc + (size_t)b * nblk;
    int ipt = (nblk + 255) >> 8;
    int s0 = t * ipt;
    int s1 = min(s0 + ipt, nblk);
    int lsum = 0;
    for (int k = s0; k < s1; ++k) lsum += p[k];
    sh[t] = lsum;
    __syncthreads();
    for (int off = 1; off < 256; off <<= 1) {
        int add = (t >= off) ? sh[t - off] : 0;
        __syncthreads();
        sh[t] += add;
        __syncthreads();
    }
    int run = sh[t] - lsum;
    for (int k = s0; k < s1; ++k) {
        int v = p[k];
        p[k] = run;
        run += v;
    }
    if (t == 255) tot[b] = sh[255];
}

// ---- pass A2b: exclusive scan of bucket totals -> base[]; zero ecw pad ----
__global__ __launch_bounds__(256) void kA_scanT(const int* __restrict__ tot,
                                                int* __restrict__ base,
                                                int2* __restrict__ ecw_pad) {
    __shared__ int sh[256];
    int t = threadIdx.x;
    int v = (t < NBUCK) ? tot[t] : 0;
    sh[t] = v;
    __syncthreads();
    for (int off = 1; off < 256; off <<= 1) {
        int add = (t >= off) ? sh[t - off] : 0;
        __syncthreads();
        sh[t] += add;
        __syncthreads();
    }
    if (t < NBUCK) base[t] = sh[t] - v;
    ecw_pad[t] = make_int2(0, 0);  // gather-overrun region, weight 0
}

// ---- pass A3: bucket-major placement via LDS staging, coalesced run flush
// tmp[pos] = { col | (row&511)<<17 , w_bits }
__global__ __launch_bounds__(256) void kA_place(const int* __restrict__ row,
                                                const int* __restrict__ col,
                                                const float* __restrict__ w,
                                                const int* __restrict__ bc,
                                                const int* __restrict__ base, int nblk,
                                                int2* __restrict__ tmp, int E) {
    __shared__ int hist[256];
    __shared__ int lbase[256];
    __shared__ int gb[256];
    __shared__ int cur[256];
    __shared__ int2 stage[CHUNK];
    __shared__ unsigned char bkt[CHUNK];
    int t = threadIdx.x;
    hist[t] = 0;
    __syncthreads();
    int g0 = blockIdx.x * CHUNK;
    int n = min(CHUNK, E - g0);
    for (int i = t; i < n; i += 256) {
        atomicAdd(&hist[row[g0 + i] >> BSHIFT], 1);
    }
    __syncthreads();
    int v = hist[t];
    lbase[t] = v;
    __syncthreads();
    for (int off = 1; off < 256; off <<= 1) {
        int add = (t >= off) ? lbase[t - off] : 0;
        __syncthreads();
        lbase[t] += add;
        __syncthreads();
    }
    int excl = lbase[t] - v;
    __syncthreads();
    lbase[t] = excl;
    cur[t] = excl;
    if (t < NBUCK) gb[t] = base[t] + bc[t * nblk + blockIdx.x];
    __syncthreads();
    for (int i = t; i < n; i += 256) {
        int r = row[g0 + i];
        int c = col[g0 + i];
        float wv = w[g0 + i];
        int b = r >> BSHIFT;
        int lp = atomicAdd(&cur[b], 1);
        stage[lp] = make_int2(c | ((r & 511) << 17), __float_as_int(wv));
        bkt[lp] = (unsigned char)b;
    }
    __syncthreads();
    for (int i = t; i < n; i += 256) {
        int b = bkt[i];
        tmp[gb[b] + (i - lbase[b])] = stage[i];
    }
}

// ---- pass A4: per-bucket deg/dinv from tmp (LDS float atomics) ----
__global__ __launch_bounds__(512) void kD_deg(const int2* __restrict__ tmp,
                                              const int* __restrict__ base,
                                              float* __restrict__ dinv, int E) {
    __shared__ float degs[512];
    int b = blockIdx.x;
    int t = threadIdx.x;
    degs[t] = 0.0f;
    __syncthreads();
    int gbase = base[b];
    int gend = (b == NBUCK - 1) ? E : base[b + 1];
    int node0 = b << BSHIFT;
    int nloc = min(512, kN - node0);
    for (int i = gbase + t; i < gend; i += 512) {
        int2 e = tmp[i];
        atomicAdd(&degs[(e.x >> 17) & 511], __int_as_float(e.y));
    }
    __syncthreads();
    if (t < nloc) {
        float d = 1.0f + degs[t];
        dinv[node0 + t] = (d > 0.0f) ? rsqrtf(d) : 0.0f;
    }
}

// ---- pass B: per-bucket fine counting sort + start[] ----
// writes FINAL ecw = {byte offset col<<7, dinv[row]*w*dinv[col]}.
__global__ __launch_bounds__(512) void kB_sort(const int2* __restrict__ tmp,
                                               const int* __restrict__ base,
                                               const float* __restrict__ dinv,
                                               int2* __restrict__ ecw,
                                               int* __restrict__ start, int E) {
    __shared__ int hist[512];
    __shared__ int cur[512];
    int b = blockIdx.x;
    int t = threadIdx.x;
    int gbase = base[b];
    int gend = (b == NBUCK - 1) ? E : base[b + 1];
    int size = gend - gbase;
    int node0 = b << BSHIFT;
    int nloc = min(512, kN - node0);
    hist[t] = 0;
    __syncthreads();
    for (int i = t; i < size; i += 512) {
        atomicAdd(&hist[(tmp[gbase + i].x >> 17) & 511], 1);
    }
    __syncthreads();
    int v = hist[t];
    hist[t] = v;
    __syncthreads();
    for (int off = 1; off < 512; off <<= 1) {
        int add = (t >= off) ? hist[t - off] : 0;
        __syncthreads();
        hist[t] += add;
        __syncthreads();
    }
    int excl = hist[t] - v;
    __syncthreads();
    cur[t] = excl;
    __syncthreads();
    if (t < nloc) start[node0 + t] = gbase + excl;
    if (b == 0 && t == 0) start[kN] = E;
    for (int i = t; i < size; i += 512) {
        int2 e = tmp[gbase + i];
        int c = e.x & 0x1FFFF;
        int rl = (e.x >> 17) & 511;
        float wn = dinv[node0 + rl] * __int_as_float(e.y) * dinv[c];
        int lp = atomicAdd(&cur[rl], 1);
        ecw[gbase + lp] = make_int2(c << 7, __float_as_int(wn));
    }
}

// ---- quad-node gather hop: 4 nodes/wave, 16 lanes each, lane=feature quad
// Each lane loads a packed bf16x4 (8B). One gather + one ecw broadcast
// retire an edge-slot for all 4 nodes. Loop bound = max degree of the 4;
// overrun reads land in a neighbor's segment / zeroed pad with weight
// predicated to 0 (exact) -- the neighbor-line touches act as prefetch.
template <typename OutWriter>
__device__ __forceinline__ void hop_body(const int* __restrict__ start,
                                         const int2* __restrict__ ecw,
                                         const float* __restrict__ dinv,
                                         const unsigned short* __restrict__ h_in,
                                         int n, OutWriter writeout) {
    int wv = threadIdx.x >> 6;
    int lane = threadIdx.x & 63;
    int q = lane >> 4;   // node-in-wave 0..3
    int f = lane & 15;   // feature quad (features 4f..4f+3)
    int node = blockIdx.x * 16 + wv * 4 + q;
    bool valid = node < n;
    int nd = valid ? node : (n - 1);
    const char* hb = (const char*)h_in;
    int lo = f << 3;  // byte offset of the feature quad in a 128B row
    float di = dinv[nd];
    float d2 = di * di;
    uint2 su = *(const uint2*)(hb + ((size_t)nd << 7) + lo);
    float acc0 = d2 * __uint_as_float(su.x << 16);
    float acc1 = d2 * __uint_as_float(su.x & 0xffff0000u);
    float acc2 = d2 * __uint_as_float(su.y << 16);
    float acc3 = d2 * __uint_as_float(su.y & 0xffff0000u);
    int s = start[nd], e = start[nd + 1];
    int d = e - s;
    int m1 = max(d, __shfl_xor(d, 16));
    int dmax = max(m1, __shfl_xor(m1, 32));  // uniform loop bound
    for (int it = 0; it < dmax; it += 4) {
        int j = s + it;
        int2 v0 = ecw[j + 0];  // unconditional: tail pad makes overrun safe
        int2 v1 = ecw[j + 1];
        int2 v2 = ecw[j + 2];
        int2 v3 = ecw[j + 3];
        uint2 g0 = *(const uint2*)(hb + (unsigned)(v0.x + lo));
        uint2 g1 = *(const uint2*)(hb + (unsigned)(v1.x + lo));
        uint2 g2 = *(const uint2*)(hb + (unsigned)(v2.x + lo));
        uint2 g3 = *(const uint2*)(hb + (unsigned)(v3.x + lo));
        float w0 = (it + 0 < d) ? __int_as_float(v0.y) : 0.0f;
        float w1 = (it + 1 < d) ? __int_as_float(v1.y) : 0.0f;
        float w2 = (it + 2 < d) ? __int_as_float(v2.y) : 0.0f;
        float w3 = (it + 3 < d) ? __int_as_float(v3.y) : 0.0f;
        acc0 = fmaf(w0, __uint_as_float(g0.x << 16), acc0);
        acc1 = fmaf(w0, __uint_as_float(g0.x & 0xffff0000u), acc1);
        acc2 = fmaf(w0, __uint_as_float(g0.y << 16), acc2);
        acc3 = fmaf(w0, __uint_as_float(g0.y & 0xffff0000u), acc3);
        acc0 = fmaf(w1, __uint_as_float(g1.x << 16), acc0);
        acc1 = fmaf(w1, __uint_as_float(g1.x & 0xffff0000u), acc1);
        acc2 = fmaf(w1, __uint_as_float(g1.y << 16), acc2);
        acc3 = fmaf(w1, __uint_as_float(g1.y & 0xffff0000u), acc3);
        acc0 = fmaf(w2, __uint_as_float(g2.x << 16), acc0);
        acc1 = fmaf(w2, __uint_as_float(g2.x & 0xffff0000u), acc1);
        acc2 = fmaf(w2, __uint_as_float(g2.y << 16), acc2);
        acc3 = fmaf(w2, __uint_as_float(g2.y & 0xffff0000u), acc3);
        acc0 = fmaf(w3, __uint_as_float(g3.x << 16), acc0);
        acc1 = fmaf(w3, __uint_as_float(g3.x & 0xffff0000u), acc1);
        acc2 = fmaf(w3, __uint_as_float(g3.y << 16), acc2);
        acc3 = fmaf(w3, __uint_as_float(g3.y & 0xffff0000u), acc3);
    }
    if (valid) writeout(node, f, acc0, acc1, acc2, acc3);
}

__global__ __launch_bounds__(256) void k_hop1(const int* __restrict__ start,
                                              const int2* __restrict__ ecw,
                                              const float* __restrict__ dinv,
                                              const unsigned short* __restrict__ h_in,
                                              uint2* __restrict__ h_out64, int n) {
    hop_body(start, ecw, dinv, h_in, n,
             [=](int node, int f, float a0, float a1, float a2, float a3) {
                 uint2 p;
                 p.x = (unsigned)f2bf(a0) | ((unsigned)f2bf(a1) << 16);
                 p.y = (unsigned)f2bf(a2) | ((unsigned)f2bf(a3) << 16);
                 h_out64[((size_t)node << 4) + f] = p;  // 16 uint2 per row
             });
}

__global__ __launch_bounds__(256) void k_hop2(const int* __restrict__ start,
                                              const int2* __restrict__ ecw,
                                              const float* __restrict__ dinv,
                                              const unsigned short* __restrict__ h_in,
                                              const float* __restrict__ bias,
                                              float* __restrict__ out, int n) {
    hop_body(start, ecw, dinv, h_in, n,
             [=](int node, int f, float a0, float a1, float a2, float a3) {
                 float4 b = *reinterpret_cast<const float4*>(bias + (f << 2));
                 float4 o = make_float4(a0 + b.x, a1 + b.y, a2 + b.z, a3 + b.w);
                 *reinterpret_cast<float4*>(out + ((size_t)node << 6) + (f << 2)) = o;
             });
}

extern "C" void kernel_launch(void* const* d_in, const int* in_sizes, int n_in,
                              void* d_out, int out_size, void* d_ws, size_t ws_size,
                              hipStream_t stream) {
    const float* x    = (const float*)d_in[0];   // (N, 64)
    const int*   ei   = (const int*)d_in[1];     // (2, E)
    const float* ew   = (const float*)d_in[2];   // (E,)
    const float* W    = (const float*)d_in[3];   // (64, 64)
    const float* bias = (const float*)d_in[4];   // (64,)
    const int E = in_sizes[1] / 2;
    const int* row = ei;       // destination
    const int* col = ei + E;   // source

    const int nblk = (E + CHUNK - 1) / CHUNK;        // 245 @ E=1M
    const int nxw  = (kN + XW_ROWS - 1) / XW_ROWS;   // 782

    // ws layout (1KB-aligned): base[256] | tot[256] | bc[NBUCK*nblk] |
    // start[kN+1] | dinv[kN] | ecw[E+pad] int2 | y bf16 | h1 bf16 (tmp=h1)
    char* ws = (char*)d_ws;
    auto alloc = [&](size_t bytes) {
        char* p = ws;
        ws += ((bytes + 1023) & ~(size_t)1023);
        return p;
    };
    int*            base  = (int*)alloc(sizeof(int) * 256);
    int*            tot   = (int*)alloc(sizeof(int) * 256);
    int*            bc    = (int*)alloc(sizeof(int) * (size_t)NBUCK * nblk);
    int*            start = (int*)alloc(sizeof(int) * (kN + 1));
    float*          dinv  = (float*)alloc(sizeof(float) * kN);
    int2*           ecw   = (int2*)alloc(sizeof(int2) * (size_t)(E + ECW_PAD));
    unsigned short* y     = (unsigned short*)alloc(sizeof(short) * (size_t)kN * kD);
    unsigned short* h1    = (unsigned short*)alloc(sizeof(short) * (size_t)kN * kD);
    int2*           tmp   = (int2*)h1;  // bucket-major staging, dead before hop1

    // fused: y = x@W  ||  per-chunk bucket histogram
    k_xw_count<<<nxw + nblk, 256, 0, stream>>>(x, W, y, row, bc, nxw, nblk, kN, E);

    // CSR build (no per-edge global atomics)
    kA_scanB<<<NBUCK, 256, 0, stream>>>(bc, tot, nblk);
    kA_scanT<<<1, 256, 0, stream>>>(tot, base, ecw + E);
    kA_place<<<nblk, 256, 0, stream>>>(row, col, ew, bc, base, nblk, tmp, E);
    kD_deg<<<NBUCK, 512, 0, stream>>>(tmp, base, dinv, E);
    kB_sort<<<NBUCK, 512, 0, stream>>>(tmp, base, dinv, ecw, start, E);

    // 2 gather hops (quad-node waves, packed bf16x4 gathers)
    k_hop1<<<(kN + 15) / 16, 256, 0, stream>>>(start, ecw, dinv, y,
                                               (uint2*)h1, kN);
    k_hop2<<<(kN + 15) / 16, 256, 0, stream>>>(start, ecw, dinv, h1, bias,
                                               (float*)d_out, kN);
}